// Round 1
// baseline (2766.934 us; speedup 1.0000x reference)
//
#include <hip/hip_runtime.h>

// Sizes (fixed by the reference):
//   B*T = 64, S = 64, Dv = 768, Da = 512, SHARED = 512
//   a,b: (64, 513) with trailing 1.0
//   fw1: (1024, 513*513), fw2: (512, 1024)
#define AB 513
#define TD 263169  // 513*513

// ---------------------------------------------------------------------------
// Kernel 1: per-modality pool-over-S + 2-layer MLP.
// Writes transposed activations outT[o*64 + bt] for o in [0,512), plus a
// ones-row at o = 512 (the concatenated 1.0 of the reference).
// ---------------------------------------------------------------------------
__global__ __launch_bounds__(256) void unimodal_kernel(
    const float* __restrict__ x,   // (64, 64, D)
    const float* __restrict__ w1,  // (512, D)
    const float* __restrict__ b1,  // (512)
    const float* __restrict__ w2,  // (512, 512)
    const float* __restrict__ b2,  // (512)
    int D,
    float* __restrict__ outT)      // (513, 64)
{
    __shared__ float p_sh[768];
    __shared__ float h_sh[512];
    const int bt = blockIdx.x;
    const int tid = threadIdx.x;
    const int lane = tid & 63, wid = tid >> 6;

    // pool: p[d] = mean over S=64
    for (int d = tid; d < D; d += 256) {
        float s = 0.f;
        const float* xp = x + (size_t)bt * 64 * D + d;
        for (int ss = 0; ss < 64; ++ss) s += xp[(size_t)ss * D];
        p_sh[d] = s * (1.0f / 64.0f);
    }
    __syncthreads();

    // h1 = relu(p @ w1^T + b1)
    for (int h = wid; h < 512; h += 4) {
        float s = 0.f;
        const float* wr = w1 + (size_t)h * D;
        for (int d = lane; d < D; d += 64) s += wr[d] * p_sh[d];
        #pragma unroll
        for (int m = 1; m < 64; m <<= 1) s += __shfl_xor(s, m, 64);
        if (lane == 0) h_sh[h] = fmaxf(s + b1[h], 0.f);
    }
    __syncthreads();

    // h2 = h1 @ w2^T + b2   (no relu), stored transposed
    for (int o = wid; o < 512; o += 4) {
        float s = 0.f;
        const float* wr = w2 + (size_t)o * 512;
        for (int d = lane; d < 512; d += 64) s += wr[d] * h_sh[d];
        #pragma unroll
        for (int m = 1; m < 64; m <<= 1) s += __shfl_xor(s, m, 64);
        if (lane == 0) outT[o * 64 + bt] = s + b2[o];
    }
    if (tid == 0) outT[512 * 64 + bt] = 1.0f;  // trailing ones
}

// ---------------------------------------------------------------------------
// Kernel 2: the big bilinear contraction.
//   h[bt, o] = relu( sum_{d,e} a[d,bt] * fw1[o, d*513+e] * b[e,bt] + fb1[o] )
// One block per o (1024 blocks), 512 threads = one column e each.
// d-loop: coalesced load of W[d,e] across lanes; a-row is wave-uniform
// (scalar loads); 64 FMAs per load. Trailing-ones structure:
//   - d = 512 row (a = 1): t[j] += w
//   - e = 512 column (b = 1, includes w11): corr pass on wave 0.
// ---------------------------------------------------------------------------
__global__ __launch_bounds__(512) void bilinear_kernel(
    const float* __restrict__ fw1,  // (1024, 263169)
    const float* __restrict__ fb1,  // (1024)
    const float* __restrict__ aT,   // (513, 64)
    const float* __restrict__ bT,   // (513, 64)
    float* __restrict__ hbuf)       // (64, 1024)
{
    __shared__ float red[8][64];
    const int o = blockIdx.x;
    const int tid = threadIdx.x;
    const int lane = tid & 63, wid = tid >> 6;
    const float* __restrict__ W = fw1 + (size_t)o * TD;
    const int e = tid;  // [0, 512)

    float t[64];
    #pragma unroll
    for (int j = 0; j < 64; ++j) t[j] = 0.f;

    // main loop over d = 0..511, software-prefetch next W element
    float w = W[e];
    for (int d = 0; d < 512; ++d) {
        const float wn = W[(d + 1) * AB + e];
        const float* __restrict__ ar = aT + d * 64;  // wave-uniform row
        #pragma unroll
        for (int j = 0; j < 64; ++j) t[j] = fmaf(ar[j], w, t[j]);
        w = wn;
    }
    // d = 512 row: a == 1  (w currently holds W[512*513 + e], the w10 row)
    #pragma unroll
    for (int j = 0; j < 64; ++j) t[j] += w;

    // scale this column's partial by b[e, bt]
    const float* __restrict__ br = bT + e * 64;
    #pragma unroll
    for (int j = 0; j < 64; ++j) t[j] *= br[j];

    // reduce across the 64 lanes of the wave (sum over this wave's e columns)
    #pragma unroll
    for (int j = 0; j < 64; ++j) {
        float v = t[j];
        #pragma unroll
        for (int m = 1; m < 64; m <<= 1) v += __shfl_xor(v, m, 64);
        t[j] = v;
    }
    if (lane == 0) {
        #pragma unroll
        for (int j = 0; j < 64; ++j) red[wid][j] = t[j];
    }
    __syncthreads();

    // wave 0: e = 512 column (b = 1), cross-wave combine, bias + relu, store
    if (wid == 0) {
        float c = 0.f;
        for (int d = 0; d < AB; ++d)
            c = fmaf(aT[d * 64 + lane], W[d * AB + 512], c);  // W col uniform
        float sum = c + fb1[o];
        #pragma unroll
        for (int ww = 0; ww < 8; ++ww) sum += red[ww][lane];
        hbuf[lane * 1024 + o] = fmaxf(sum, 0.f);  // lane == bt
    }
}

// ---------------------------------------------------------------------------
// Kernel 3a: fused[bt, f] = h[bt, :] @ fw2[f, :] + fb2[f]
// ---------------------------------------------------------------------------
__global__ __launch_bounds__(256) void fuse2_kernel(
    const float* __restrict__ hbuf,  // (64, 1024)
    const float* __restrict__ fw2,   // (512, 1024)
    const float* __restrict__ fb2,   // (512)
    float* __restrict__ fused)       // (64, 512)
{
    __shared__ float h_sh[1024];
    const int bt = blockIdx.x, tid = threadIdx.x;
    const int lane = tid & 63, wid = tid >> 6;
    for (int o = tid; o < 1024; o += 256) h_sh[o] = hbuf[bt * 1024 + o];
    __syncthreads();
    for (int f = wid; f < 512; f += 4) {
        float s = 0.f;
        const float* wr = fw2 + (size_t)f * 1024;
        for (int o = lane; o < 1024; o += 64) s += wr[o] * h_sh[o];
        #pragma unroll
        for (int m = 1; m < 64; m <<= 1) s += __shfl_xor(s, m, 64);
        if (lane == 0) fused[bt * 512 + f] = s + fb2[f];
    }
}

// ---------------------------------------------------------------------------
// Kernel 3b: LIF over the time axis. 1024 independent (b, d) chains, T = 32.
//   mem = 0.9*mem + x;  s = (mem >= 1);  mem -= s
// ---------------------------------------------------------------------------
__global__ __launch_bounds__(256) void lif_kernel(
    const float* __restrict__ fused,  // (2, 32, 512) flattened
    float* __restrict__ out)          // (2, 32, 512)
{
    const int idx = blockIdx.x * 256 + threadIdx.x;
    if (idx >= 1024) return;
    const int b = idx >> 9, dd = idx & 511;
    float mem = 0.f;
    for (int t = 0; t < 32; ++t) {
        const size_t off = ((size_t)(b * 32 + t) * 512) + dd;
        mem = 0.9f * mem + fused[off];
        const float s = (mem >= 1.0f) ? 1.0f : 0.0f;
        out[off] = s;
        mem -= s;
    }
}

// ---------------------------------------------------------------------------
extern "C" void kernel_launch(void* const* d_in, const int* in_sizes, int n_in,
                              void* d_out, int out_size, void* d_ws, size_t ws_size,
                              hipStream_t stream) {
    const float* vision = (const float*)d_in[0];
    const float* audio  = (const float*)d_in[1];
    const float* vw1 = (const float*)d_in[2];
    const float* vb1 = (const float*)d_in[3];
    const float* vw2 = (const float*)d_in[4];
    const float* vb2 = (const float*)d_in[5];
    const float* aw1 = (const float*)d_in[6];
    const float* ab1 = (const float*)d_in[7];
    const float* aw2 = (const float*)d_in[8];
    const float* ab2 = (const float*)d_in[9];
    const float* fw1 = (const float*)d_in[10];
    const float* fb1 = (const float*)d_in[11];
    const float* fw2 = (const float*)d_in[12];
    const float* fb2 = (const float*)d_in[13];
    float* out = (float*)d_out;

    // workspace layout (floats): aT(513*64) | bT(513*64) | hbuf(64*1024) | fused(64*512)
    float* ws    = (float*)d_ws;
    float* aT    = ws;
    float* bT    = aT + AB * 64;
    float* hbuf  = bT + AB * 64;
    float* fused = hbuf + 64 * 1024;

    unimodal_kernel<<<64, 256, 0, stream>>>(vision, vw1, vb1, vw2, vb2, 768, aT);
    unimodal_kernel<<<64, 256, 0, stream>>>(audio,  aw1, ab1, aw2, ab2, 512, bT);
    bilinear_kernel<<<1024, 512, 0, stream>>>(fw1, fb1, aT, bT, hbuf);
    fuse2_kernel<<<64, 256, 0, stream>>>(hbuf, fw2, fb2, fused);
    lif_kernel<<<4, 256, 0, stream>>>(fused, out);
}

// Round 2
// 1237.389 us; speedup vs baseline: 2.2361x; 2.2361x over previous
//
#include <hip/hip_runtime.h>

#define AB 513
#define TD 263169  // 513*513

typedef float f4 __attribute__((ext_vector_type(4)));
#define GAS __attribute__((address_space(1)))
#define LAS __attribute__((address_space(3)))

// ---------------------------------------------------------------------------
// Kernel 1: both modalities. Blocks 0..63 = vision bt, 64..127 = audio bt.
// pool-over-S (float4) + 2-layer MLP with 8-outputs-per-wave ILP batching.
// Writes transposed activations outT[o*64 + bt], plus ones-row at o=512.
// ---------------------------------------------------------------------------
__global__ __launch_bounds__(256) void unimodal_kernel(
    const float* __restrict__ vx, const float* __restrict__ ax,
    const float* __restrict__ vw1, const float* __restrict__ vb1,
    const float* __restrict__ vw2, const float* __restrict__ vb2,
    const float* __restrict__ aw1, const float* __restrict__ ab1,
    const float* __restrict__ aw2, const float* __restrict__ ab2,
    float* __restrict__ aTout, float* __restrict__ bTout)
{
    const int isA = (blockIdx.x >= 64);
    const int bt = blockIdx.x & 63;
    const float* x  = isA ? ax  : vx;
    const float* w1 = isA ? aw1 : vw1;
    const float* b1 = isA ? ab1 : vb1;
    const float* w2 = isA ? aw2 : vw2;
    const float* b2 = isA ? ab2 : vb2;
    float* outT = isA ? bTout : aTout;
    const int D = isA ? 512 : 768;

    __shared__ float p_sh[768];
    __shared__ float h_sh[512];
    const int tid = threadIdx.x;
    const int lane = tid & 63, wid = tid >> 6;

    // pool: p[d] = mean over S=64, float4 per thread
    const int nd4 = D >> 2;
    for (int d4 = tid; d4 < nd4; d4 += 256) {
        f4 s = {0.f, 0.f, 0.f, 0.f};
        const float* xp = x + (size_t)bt * 64 * D + d4 * 4;
        for (int ss = 0; ss < 64; ++ss) {
            f4 v = *(const f4*)(xp + (size_t)ss * D);
            s += v;
        }
        *(f4*)&p_sh[d4 * 4] = s * 0.015625f;
    }
    __syncthreads();

    // layer1: relu(p @ w1^T + b1); 8 h-rows per wave pass
    const int nit = D >> 8;  // 3 (vision) or 2 (audio) iterations of lane*4
    for (int h0 = wid * 8; h0 < 512; h0 += 32) {
        float s[8];
        #pragma unroll
        for (int k = 0; k < 8; ++k) s[k] = 0.f;
        for (int it = 0; it < nit; ++it) {
            const int d = it * 256 + lane * 4;
            const f4 p = *(const f4*)&p_sh[d];
            #pragma unroll
            for (int k = 0; k < 8; ++k) {
                const f4 w = *(const f4*)&w1[(size_t)(h0 + k) * D + d];
                s[k] = fmaf(w[0], p[0], fmaf(w[1], p[1],
                       fmaf(w[2], p[2], fmaf(w[3], p[3], s[k]))));
            }
        }
        #pragma unroll
        for (int k = 0; k < 8; ++k) {
            float v = s[k];
            #pragma unroll
            for (int m = 1; m < 64; m <<= 1) v += __shfl_xor(v, m, 64);
            if (lane == 0) h_sh[h0 + k] = fmaxf(v + b1[h0 + k], 0.f);
        }
    }
    __syncthreads();

    // layer2: h1 @ w2^T + b2 (no relu), transposed store
    for (int h0 = wid * 8; h0 < 512; h0 += 32) {
        float s[8];
        #pragma unroll
        for (int k = 0; k < 8; ++k) s[k] = 0.f;
        for (int it = 0; it < 2; ++it) {
            const int d = it * 256 + lane * 4;
            const f4 p = *(const f4*)&h_sh[d];
            #pragma unroll
            for (int k = 0; k < 8; ++k) {
                const f4 w = *(const f4*)&w2[(size_t)(h0 + k) * 512 + d];
                s[k] = fmaf(w[0], p[0], fmaf(w[1], p[1],
                       fmaf(w[2], p[2], fmaf(w[3], p[3], s[k]))));
            }
        }
        #pragma unroll
        for (int k = 0; k < 8; ++k) {
            float v = s[k];
            #pragma unroll
            for (int m = 1; m < 64; m <<= 1) v += __shfl_xor(v, m, 64);
            if (lane == 0) outT[(h0 + k) * 64 + bt] = v + b2[h0 + k];
        }
    }
    if (tid == 0) outT[512 * 64 + bt] = 1.0f;
}

// ---------------------------------------------------------------------------
// Kernel 2: bilinear h[bt,o] = relu( a^T W_o b + fb1[o] ).
// Grid 512 blocks x 512 thr; block handles o = {2bx, 2bx+1} sequentially.
// lane = e-group (8 e), wave = bt-group (8 bt), acc[8][8] in VGPRs.
// W rows staged to LDS (double-buffered, global_load_lds); a wave-uniform.
// ---------------------------------------------------------------------------
__global__ __launch_bounds__(512, 4) void bilinear_kernel(
    const float* __restrict__ fw1,  // (1024, 263169)
    const float* __restrict__ fb1,  // (1024)
    const float* __restrict__ aT,   // (513, 64)
    const float* __restrict__ bT,   // (513, 64)
    float* __restrict__ hbuf)       // (64, 1024)
{
    __shared__ float wbuf[2][8 * 512];
    const int tid = threadIdx.x;
    const int lane = tid & 63, wid = tid >> 6;
    const int e0 = lane * 8;    // this thread's 8 e-columns
    const int bt0 = wid * 8;    // this wave's 8 bt rows

    // stage one 8-row chunk (rows d0..d0+7, e 0..511) into wbuf[buf]:
    // sweep s stages row s: 512 lanes x 4B, linear LDS.
    #define STAGE(buf, Wc)                                                    \
        do {                                                                  \
            _Pragma("unroll")                                                 \
            for (int s_ = 0; s_ < 8; ++s_) {                                  \
                const float* _src = (Wc) + s_ * AB + tid;                     \
                __builtin_amdgcn_global_load_lds(                             \
                    (const GAS uint32_t*)(const void*)_src,                   \
                    (LAS uint32_t*)(void*)&wbuf[buf][s_ * 512 + tid], 4, 0, 0);\
            }                                                                 \
        } while (0)

    for (int ooi = 0; ooi < 2; ++ooi) {
        const int o = blockIdx.x * 2 + ooi;
        const float* __restrict__ W = fw1 + (size_t)o * TD;

        float acc[8][8];
        #pragma unroll
        for (int i = 0; i < 8; ++i)
            #pragma unroll
            for (int j = 0; j < 8; ++j) acc[i][j] = 0.f;

        STAGE(0, W);
        __syncthreads();

        for (int c = 0; c < 64; ++c) {
            const int cur = c & 1;
            if (c + 1 < 64) STAGE(cur ^ 1, W + (size_t)(c + 1) * 8 * AB);

            const float* aTc = aT + c * 8 * 64 + bt0;
            #pragma unroll
            for (int dd = 0; dd < 8; ++dd) {
                const f4 a01 = *(const f4*)(aTc + dd * 64);
                const f4 a23 = *(const f4*)(aTc + dd * 64 + 4);
                const f4 w0 = *(const f4*)&wbuf[cur][dd * 512 + e0];
                const f4 w1v = *(const f4*)&wbuf[cur][dd * 512 + e0 + 4];
                #pragma unroll
                for (int j = 0; j < 4; ++j) {
                    const float av = a01[j];
                    #pragma unroll
                    for (int i = 0; i < 4; ++i) {
                        acc[i][j] = fmaf(w0[i], av, acc[i][j]);
                        acc[i + 4][j] = fmaf(w1v[i], av, acc[i + 4][j]);
                    }
                }
                #pragma unroll
                for (int j = 0; j < 4; ++j) {
                    const float av = a23[j];
                    #pragma unroll
                    for (int i = 0; i < 4; ++i) {
                        acc[i][j + 4] = fmaf(w0[i], av, acc[i][j + 4]);
                        acc[i + 4][j + 4] = fmaf(w1v[i], av, acc[i + 4][j + 4]);
                    }
                }
            }
            __syncthreads();  // drains vmcnt (staging) + waits all readers
        }

        // d = 512 row: a == 1
        {
            const f4 r0 = *(const f4*)(W + (size_t)512 * AB + e0);
            const f4 r1 = *(const f4*)(W + (size_t)512 * AB + e0 + 4);
            #pragma unroll
            for (int j = 0; j < 8; ++j)
                #pragma unroll
                for (int i = 0; i < 4; ++i) {
                    acc[i][j] += r0[i];
                    acc[i + 4][j] += r1[i];
                }
        }

        // e = 512 column (b == 1), d split across lanes; includes d=512 (a=1)
        float t[8];
        #pragma unroll
        for (int j = 0; j < 8; ++j) t[j] = 0.f;
        #pragma unroll
        for (int k = 0; k < 8; ++k) {
            const int d = k * 64 + lane;
            const float wv = W[(size_t)d * AB + 512];
            const float* ar = aT + d * 64 + bt0;
            const f4 a01 = *(const f4*)ar;
            const f4 a23 = *(const f4*)(ar + 4);
            #pragma unroll
            for (int j = 0; j < 4; ++j) {
                t[j] = fmaf(a01[j], wv, t[j]);
                t[j + 4] = fmaf(a23[j], wv, t[j + 4]);
            }
        }
        if (lane == 0) {
            const float wl = W[(size_t)512 * AB + 512];
            #pragma unroll
            for (int j = 0; j < 8; ++j) t[j] += wl;
        }

        // scale by b and fold e-tile into t
        #pragma unroll
        for (int i = 0; i < 8; ++i) {
            const float* br = bT + (size_t)(e0 + i) * 64 + bt0;
            const f4 b01 = *(const f4*)br;
            const f4 b23 = *(const f4*)(br + 4);
            #pragma unroll
            for (int j = 0; j < 4; ++j) {
                t[j] = fmaf(acc[i][j], b01[j], t[j]);
                t[j + 4] = fmaf(acc[i][j + 4], b23[j], t[j + 4]);
            }
        }

        // reduce across 64 lanes (e-groups)
        #pragma unroll
        for (int j = 0; j < 8; ++j) {
            float v = t[j];
            #pragma unroll
            for (int m = 1; m < 64; m <<= 1) v += __shfl_xor(v, m, 64);
            t[j] = v;
        }
        if (lane == 0) {
            const float bias = fb1[o];
            #pragma unroll
            for (int j = 0; j < 8; ++j)
                hbuf[(size_t)(bt0 + j) * 1024 + o] = fmaxf(t[j] + bias, 0.f);
        }
        __syncthreads();  // protect wbuf before next o's prologue
    }
    #undef STAGE
}

// ---------------------------------------------------------------------------
// Kernel 3a: fused[bt, f] = h[bt, :] @ fw2[f, :] + fb2[f]
// ---------------------------------------------------------------------------
__global__ __launch_bounds__(256) void fuse2_kernel(
    const float* __restrict__ hbuf,  // (64, 1024)
    const float* __restrict__ fw2,   // (512, 1024)
    const float* __restrict__ fb2,   // (512)
    float* __restrict__ fused)       // (64, 512)
{
    __shared__ float h_sh[1024];
    const int bt = blockIdx.x, tid = threadIdx.x;
    const int lane = tid & 63, wid = tid >> 6;
    *(f4*)&h_sh[tid * 4] = *(const f4*)&hbuf[bt * 1024 + tid * 4];
    __syncthreads();
    for (int f0 = wid * 8; f0 < 512; f0 += 32) {
        float s[8];
        #pragma unroll
        for (int k = 0; k < 8; ++k) s[k] = 0.f;
        #pragma unroll
        for (int it = 0; it < 4; ++it) {
            const int d = it * 256 + lane * 4;
            const f4 p = *(const f4*)&h_sh[d];
            #pragma unroll
            for (int k = 0; k < 8; ++k) {
                const f4 w = *(const f4*)&fw2[(size_t)(f0 + k) * 1024 + d];
                s[k] = fmaf(w[0], p[0], fmaf(w[1], p[1],
                       fmaf(w[2], p[2], fmaf(w[3], p[3], s[k]))));
            }
        }
        #pragma unroll
        for (int k = 0; k < 8; ++k) {
            float v = s[k];
            #pragma unroll
            for (int m = 1; m < 64; m <<= 1) v += __shfl_xor(v, m, 64);
            if (lane == 0) fused[bt * 512 + f0 + k] = v + fb2[f0 + k];
        }
    }
}

// ---------------------------------------------------------------------------
// Kernel 3b: LIF over time. 1024 independent (b, d) chains, T = 32.
// ---------------------------------------------------------------------------
__global__ __launch_bounds__(256) void lif_kernel(
    const float* __restrict__ fused,  // (2, 32, 512)
    float* __restrict__ out)          // (2, 32, 512)
{
    const int idx = blockIdx.x * 256 + threadIdx.x;
    if (idx >= 1024) return;
    const int b = idx >> 9, dd = idx & 511;
    float mem = 0.f;
    for (int t = 0; t < 32; ++t) {
        const size_t off = ((size_t)(b * 32 + t) * 512) + dd;
        mem = 0.9f * mem + fused[off];
        const float s = (mem >= 1.0f) ? 1.0f : 0.0f;
        out[off] = s;
        mem -= s;
    }
}

// ---------------------------------------------------------------------------
extern "C" void kernel_launch(void* const* d_in, const int* in_sizes, int n_in,
                              void* d_out, int out_size, void* d_ws, size_t ws_size,
                              hipStream_t stream) {
    const float* vision = (const float*)d_in[0];
    const float* audio  = (const float*)d_in[1];
    const float* vw1 = (const float*)d_in[2];
    const float* vb1 = (const float*)d_in[3];
    const float* vw2 = (const float*)d_in[4];
    const float* vb2 = (const float*)d_in[5];
    const float* aw1 = (const float*)d_in[6];
    const float* ab1 = (const float*)d_in[7];
    const float* aw2 = (const float*)d_in[8];
    const float* ab2 = (const float*)d_in[9];
    const float* fw1 = (const float*)d_in[10];
    const float* fb1 = (const float*)d_in[11];
    const float* fw2 = (const float*)d_in[12];
    const float* fb2 = (const float*)d_in[13];
    float* out = (float*)d_out;

    float* ws    = (float*)d_ws;
    float* aT    = ws;                 // 513*64
    float* bT    = aT + AB * 64;       // 513*64
    float* hbuf  = bT + AB * 64;       // 64*1024
    float* fused = hbuf + 64 * 1024;   // 64*512

    unimodal_kernel<<<128, 256, 0, stream>>>(vision, audio,
        vw1, vb1, vw2, vb2, aw1, ab1, aw2, ab2, aT, bT);
    bilinear_kernel<<<512, 512, 0, stream>>>(fw1, fb1, aT, bT, hbuf);
    fuse2_kernel<<<64, 256, 0, stream>>>(hbuf, fw2, fb2, fused);
    lif_kernel<<<4, 256, 0, stream>>>(fused, out);
}

// Round 3
// 804.802 us; speedup vs baseline: 3.4380x; 1.5375x over previous
//
#include <hip/hip_runtime.h>

#define AB 513
#define TD 263169  // 513*513

typedef float f4 __attribute__((ext_vector_type(4)));
#define GAS __attribute__((address_space(1)))
#define LAS __attribute__((address_space(3)))

// ---------------------------------------------------------------------------
// Kernel 1: both modalities. Blocks 0..63 = vision bt, 64..127 = audio bt.
// ---------------------------------------------------------------------------
__global__ __launch_bounds__(256) void unimodal_kernel(
    const float* __restrict__ vx, const float* __restrict__ ax,
    const float* __restrict__ vw1, const float* __restrict__ vb1,
    const float* __restrict__ vw2, const float* __restrict__ vb2,
    const float* __restrict__ aw1, const float* __restrict__ ab1,
    const float* __restrict__ aw2, const float* __restrict__ ab2,
    float* __restrict__ aTout, float* __restrict__ bTout)
{
    const int isA = (blockIdx.x >= 64);
    const int bt = blockIdx.x & 63;
    const float* x  = isA ? ax  : vx;
    const float* w1 = isA ? aw1 : vw1;
    const float* b1 = isA ? ab1 : vb1;
    const float* w2 = isA ? aw2 : vw2;
    const float* b2 = isA ? ab2 : vb2;
    float* outT = isA ? bTout : aTout;
    const int D = isA ? 512 : 768;

    __shared__ float p_sh[768];
    __shared__ float h_sh[512];
    const int tid = threadIdx.x;
    const int lane = tid & 63, wid = tid >> 6;

    const int nd4 = D >> 2;
    for (int d4 = tid; d4 < nd4; d4 += 256) {
        f4 s = {0.f, 0.f, 0.f, 0.f};
        const float* xp = x + (size_t)bt * 64 * D + d4 * 4;
        for (int ss = 0; ss < 64; ++ss) {
            f4 v = *(const f4*)(xp + (size_t)ss * D);
            s += v;
        }
        *(f4*)&p_sh[d4 * 4] = s * 0.015625f;
    }
    __syncthreads();

    const int nit = D >> 8;
    for (int h0 = wid * 8; h0 < 512; h0 += 32) {
        float s[8];
        #pragma unroll
        for (int k = 0; k < 8; ++k) s[k] = 0.f;
        for (int it = 0; it < nit; ++it) {
            const int d = it * 256 + lane * 4;
            const f4 p = *(const f4*)&p_sh[d];
            #pragma unroll
            for (int k = 0; k < 8; ++k) {
                const f4 w = *(const f4*)&w1[(size_t)(h0 + k) * D + d];
                s[k] = fmaf(w[0], p[0], fmaf(w[1], p[1],
                       fmaf(w[2], p[2], fmaf(w[3], p[3], s[k]))));
            }
        }
        #pragma unroll
        for (int k = 0; k < 8; ++k) {
            float v = s[k];
            #pragma unroll
            for (int m = 1; m < 64; m <<= 1) v += __shfl_xor(v, m, 64);
            if (lane == 0) h_sh[h0 + k] = fmaxf(v + b1[h0 + k], 0.f);
        }
    }
    __syncthreads();

    for (int h0 = wid * 8; h0 < 512; h0 += 32) {
        float s[8];
        #pragma unroll
        for (int k = 0; k < 8; ++k) s[k] = 0.f;
        for (int it = 0; it < 2; ++it) {
            const int d = it * 256 + lane * 4;
            const f4 p = *(const f4*)&h_sh[d];
            #pragma unroll
            for (int k = 0; k < 8; ++k) {
                const f4 w = *(const f4*)&w2[(size_t)(h0 + k) * 512 + d];
                s[k] = fmaf(w[0], p[0], fmaf(w[1], p[1],
                       fmaf(w[2], p[2], fmaf(w[3], p[3], s[k]))));
            }
        }
        #pragma unroll
        for (int k = 0; k < 8; ++k) {
            float v = s[k];
            #pragma unroll
            for (int m = 1; m < 64; m <<= 1) v += __shfl_xor(v, m, 64);
            if (lane == 0) outT[(h0 + k) * 64 + bt] = v + b2[h0 + k];
        }
    }
    if (tid == 0) outT[512 * 64 + bt] = 1.0f;
}

// ---------------------------------------------------------------------------
// Kernel 2: bilinear h[bt,o] = relu( a^T W_o b + fb1[o] ).
// Grid 512 blocks x 512 thr; block handles o = {2bx, 2bx+1} sequentially.
// Thread e-set: {4*lane..4*lane+3} U {256+4*lane..} (conflict-free b128).
// Wave = bt-group of 8. acc[8][8] in VGPRs (launch_bounds(512,2) -> 128 cap).
// W chunk (8 rows x 512 e) and a chunk (8 d x 64 bt) double-buffered in LDS
// via width-16 global_load_lds; inner loop is pure LDS + FMA.
// ---------------------------------------------------------------------------
__global__ __launch_bounds__(512, 2) void bilinear_kernel(
    const float* __restrict__ fw1,  // (1024, 263169)
    const float* __restrict__ fb1,  // (1024)
    const float* __restrict__ aT,   // (513, 64)
    const float* __restrict__ bT,   // (513, 64)
    float* __restrict__ hbuf)       // (64, 1024)
{
    __shared__ float wbuf[2][8 * 512];
    __shared__ float abuf[2][8 * 64];
    const int tid = threadIdx.x;
    const int lane = tid & 63, wid = tid >> 6;
    const int bt0 = wid * 8;
    const int el = lane * 4;  // first e-quad; second at el + 256

    // W chunk stage: 8 rows x 512 floats; width-16; dest linear in tid.
    #define STAGE(buf, Wc)                                                     \
        do {                                                                   \
            _Pragma("unroll")                                                  \
            for (int s_ = 0; s_ < 2; ++s_) {                                   \
                const int row_ = s_ * 4 + (tid >> 7);                          \
                const int col_ = (tid & 127) * 4;                              \
                __builtin_amdgcn_global_load_lds(                              \
                    (const GAS uint32_t*)(const void*)((Wc) + (size_t)row_ * AB + col_), \
                    (LAS uint32_t*)(void*)&wbuf[buf][row_ * 512 + col_], 16, 0, 0); \
            }                                                                  \
        } while (0)
    // a chunk stage: 512 consecutive floats (rows c*8..c*8+7 of aT).
    #define ASTAGE(buf, c_)                                                    \
        __builtin_amdgcn_global_load_lds(                                      \
            (const GAS uint32_t*)(const void*)(aT + (size_t)(c_) * 512 + tid), \
            (LAS uint32_t*)(void*)&abuf[buf][tid], 4, 0, 0)

    for (int ooi = 0; ooi < 2; ++ooi) {
        const int o = blockIdx.x * 2 + ooi;
        const float* __restrict__ W = fw1 + (size_t)o * TD;

        float acc[8][8];
        #pragma unroll
        for (int i = 0; i < 8; ++i)
            #pragma unroll
            for (int j = 0; j < 8; ++j) acc[i][j] = 0.f;

        STAGE(0, W);
        ASTAGE(0, 0);
        __syncthreads();

        for (int c = 0; c < 64; ++c) {
            const int cur = c & 1;
            if (c + 1 < 64) {
                STAGE(cur ^ 1, W + (size_t)(c + 1) * 8 * AB);
                ASTAGE(cur ^ 1, c + 1);
            }

            #pragma unroll
            for (int dd = 0; dd < 8; ++dd) {
                const f4 a01 = *(const f4*)&abuf[cur][dd * 64 + bt0];      // broadcast
                const f4 a23 = *(const f4*)&abuf[cur][dd * 64 + bt0 + 4];  // broadcast
                const f4 w0  = *(const f4*)&wbuf[cur][dd * 512 + el];
                const f4 w1v = *(const f4*)&wbuf[cur][dd * 512 + el + 256];
                #pragma unroll
                for (int j = 0; j < 4; ++j) {
                    const float av = a01[j];
                    #pragma unroll
                    for (int i = 0; i < 4; ++i) {
                        acc[i][j] = fmaf(w0[i], av, acc[i][j]);
                        acc[i + 4][j] = fmaf(w1v[i], av, acc[i + 4][j]);
                    }
                }
                #pragma unroll
                for (int j = 0; j < 4; ++j) {
                    const float av = a23[j];
                    #pragma unroll
                    for (int i = 0; i < 4; ++i) {
                        acc[i][j + 4] = fmaf(w0[i], av, acc[i][j + 4]);
                        acc[i + 4][j + 4] = fmaf(w1v[i], av, acc[i + 4][j + 4]);
                    }
                }
            }
            __syncthreads();
        }

        // d = 512 row: a == 1
        {
            const f4 r0 = *(const f4*)(W + (size_t)512 * AB + el);
            const f4 r1 = *(const f4*)(W + (size_t)512 * AB + el + 256);
            #pragma unroll
            for (int j = 0; j < 8; ++j)
                #pragma unroll
                for (int i = 0; i < 4; ++i) {
                    acc[i][j] += r0[i];
                    acc[i + 4][j] += r1[i];
                }
        }

        // e = 512 column (b == 1), d split across lanes; includes d=512 (a=1)
        float t[8];
        #pragma unroll
        for (int j = 0; j < 8; ++j) t[j] = 0.f;
        #pragma unroll
        for (int k = 0; k < 8; ++k) {
            const int d = k * 64 + lane;
            const float wv = W[(size_t)d * AB + 512];
            const float* ar = aT + d * 64 + bt0;
            const f4 a01 = *(const f4*)ar;
            const f4 a23 = *(const f4*)(ar + 4);
            #pragma unroll
            for (int j = 0; j < 4; ++j) {
                t[j] = fmaf(a01[j], wv, t[j]);
                t[j + 4] = fmaf(a23[j], wv, t[j + 4]);
            }
        }
        if (lane == 0) {
            const float wl = W[(size_t)512 * AB + 512];
            #pragma unroll
            for (int j = 0; j < 8; ++j) t[j] += wl;
        }

        // scale by b and fold e-tile into t
        #pragma unroll
        for (int i = 0; i < 8; ++i) {
            const int e = (i < 4) ? (el + i) : (256 + el + (i - 4));
            const float* br = bT + (size_t)e * 64 + bt0;
            const f4 b01 = *(const f4*)br;
            const f4 b23 = *(const f4*)(br + 4);
            #pragma unroll
            for (int j = 0; j < 4; ++j) {
                t[j] = fmaf(acc[i][j], b01[j], t[j]);
                t[j + 4] = fmaf(acc[i][j + 4], b23[j], t[j + 4]);
            }
        }

        // reduce across 64 lanes (e-groups)
        #pragma unroll
        for (int j = 0; j < 8; ++j) {
            float v = t[j];
            #pragma unroll
            for (int m = 1; m < 64; m <<= 1) v += __shfl_xor(v, m, 64);
            t[j] = v;
        }
        if (lane == 0) {
            const float bias = fb1[o];
            #pragma unroll
            for (int j = 0; j < 8; ++j)
                hbuf[(size_t)(bt0 + j) * 1024 + o] = fmaxf(t[j] + bias, 0.f);
        }
        __syncthreads();  // protect wbuf/abuf before next o's prologue
    }
    #undef STAGE
    #undef ASTAGE
}

// ---------------------------------------------------------------------------
// Kernel 3a: fused[bt, f] = h[bt, :] @ fw2[f, :] + fb2[f]
// ---------------------------------------------------------------------------
__global__ __launch_bounds__(256) void fuse2_kernel(
    const float* __restrict__ hbuf,  // (64, 1024)
    const float* __restrict__ fw2,   // (512, 1024)
    const float* __restrict__ fb2,   // (512)
    float* __restrict__ fused)       // (64, 512)
{
    __shared__ float h_sh[1024];
    const int bt = blockIdx.x, tid = threadIdx.x;
    const int lane = tid & 63, wid = tid >> 6;
    *(f4*)&h_sh[tid * 4] = *(const f4*)&hbuf[bt * 1024 + tid * 4];
    __syncthreads();
    for (int f0 = wid * 8; f0 < 512; f0 += 32) {
        float s[8];
        #pragma unroll
        for (int k = 0; k < 8; ++k) s[k] = 0.f;
        #pragma unroll
        for (int it = 0; it < 4; ++it) {
            const int d = it * 256 + lane * 4;
            const f4 p = *(const f4*)&h_sh[d];
            #pragma unroll
            for (int k = 0; k < 8; ++k) {
                const f4 w = *(const f4*)&fw2[(size_t)(f0 + k) * 1024 + d];
                s[k] = fmaf(w[0], p[0], fmaf(w[1], p[1],
                       fmaf(w[2], p[2], fmaf(w[3], p[3], s[k]))));
            }
        }
        #pragma unroll
        for (int k = 0; k < 8; ++k) {
            float v = s[k];
            #pragma unroll
            for (int m = 1; m < 64; m <<= 1) v += __shfl_xor(v, m, 64);
            if (lane == 0) fused[bt * 512 + f0 + k] = v + fb2[f0 + k];
        }
    }
}

// ---------------------------------------------------------------------------
// Kernel 3b: LIF over time. 1024 independent (b, d) chains, T = 32.
// ---------------------------------------------------------------------------
__global__ __launch_bounds__(256) void lif_kernel(
    const float* __restrict__ fused,  // (2, 32, 512)
    float* __restrict__ out)          // (2, 32, 512)
{
    const int idx = blockIdx.x * 256 + threadIdx.x;
    if (idx >= 1024) return;
    const int b = idx >> 9, dd = idx & 511;
    float mem = 0.f;
    for (int t = 0; t < 32; ++t) {
        const size_t off = ((size_t)(b * 32 + t) * 512) + dd;
        mem = 0.9f * mem + fused[off];
        const float s = (mem >= 1.0f) ? 1.0f : 0.0f;
        out[off] = s;
        mem -= s;
    }
}

// ---------------------------------------------------------------------------
extern "C" void kernel_launch(void* const* d_in, const int* in_sizes, int n_in,
                              void* d_out, int out_size, void* d_ws, size_t ws_size,
                              hipStream_t stream) {
    const float* vision = (const float*)d_in[0];
    const float* audio  = (const float*)d_in[1];
    const float* vw1 = (const float*)d_in[2];
    const float* vb1 = (const float*)d_in[3];
    const float* vw2 = (const float*)d_in[4];
    const float* vb2 = (const float*)d_in[5];
    const float* aw1 = (const float*)d_in[6];
    const float* ab1 = (const float*)d_in[7];
    const float* aw2 = (const float*)d_in[8];
    const float* ab2 = (const float*)d_in[9];
    const float* fw1 = (const float*)d_in[10];
    const float* fb1 = (const float*)d_in[11];
    const float* fw2 = (const float*)d_in[12];
    const float* fb2 = (const float*)d_in[13];
    float* out = (float*)d_out;

    float* ws    = (float*)d_ws;
    float* aT    = ws;                 // 513*64
    float* bT    = aT + AB * 64;       // 513*64
    float* hbuf  = bT + AB * 64;       // 64*1024
    float* fused = hbuf + 64 * 1024;   // 64*512

    unimodal_kernel<<<128, 256, 0, stream>>>(vision, audio,
        vw1, vb1, vw2, vb2, aw1, ab1, aw2, ab2, aT, bT);
    bilinear_kernel<<<512, 512, 0, stream>>>(fw1, fb1, aT, bT, hbuf);
    fuse2_kernel<<<64, 256, 0, stream>>>(hbuf, fw2, fb2, fused);
    lif_kernel<<<4, 256, 0, stream>>>(fused, out);
}